// Round 1
// baseline (478.825 us; speedup 1.0000x reference)
//
#include <hip/hip_runtime.h>
#include <hip/hip_bf16.h>

#define T_STEPS 512
#define BATCH 32
#define NST 64
#define DIM 1024

__device__ __forceinline__ float fast_sigmoid(float x) {
  return __builtin_amdgcn_rcpf(1.0f + __expf(-x));
}

// ---------------- Projection GEMM ----------------
// proj[m][g*64+n] = dot(x[m][0:1024], W_g[n][0:1024])
// m = t*BATCH+b in [0,16384); g in [0,4) selected by blockIdx.y
// Block: 64 (m) x 64 (n) tile, BK=16, 256 threads, 4x4 outputs/thread.
__global__ __launch_bounds__(256) void proj_gemm(
    const float* __restrict__ x, const float* __restrict__ Wk,
    const float* __restrict__ Wv, const float* __restrict__ Wq,
    const float* __restrict__ Wa, float* __restrict__ proj) {
  const int g = blockIdx.y;
  const float* W = (g == 0) ? Wk : (g == 1) ? Wv : (g == 2) ? Wq : Wa;
  const int bm0 = blockIdx.x * 64;
  const int tid = threadIdx.x;
  const int tn = tid & 15;   // 0..15 -> n chunk
  const int tm = tid >> 4;   // 0..15 -> m chunk

  // k-major LDS tiles; stride 68 floats = 272 B = 17*16 B (float4-aligned, pads banks)
  __shared__ __align__(16) float xs[16][68];
  __shared__ __align__(16) float ws[16][68];

  float acc[4][4] = {{0.f, 0.f, 0.f, 0.f}, {0.f, 0.f, 0.f, 0.f},
                     {0.f, 0.f, 0.f, 0.f}, {0.f, 0.f, 0.f, 0.f}};

  // staging assignment: each thread loads one float4 of x and one of W per K-tile
  const int ml = tid >> 2;          // 0..63 (row within tile)
  const int k4 = (tid & 3) << 2;    // 0,4,8,12 (k offset)
  const float* xrow = x + (size_t)(bm0 + ml) * DIM + k4;
  const float* wrow = W + (size_t)ml * DIM + k4;

  for (int k0 = 0; k0 < DIM; k0 += 16) {
    float4 xv = *(const float4*)(xrow + k0);
    float4 wv = *(const float4*)(wrow + k0);
    __syncthreads();  // previous tile's reads complete before overwrite
    xs[k4 + 0][ml] = xv.x; xs[k4 + 1][ml] = xv.y;
    xs[k4 + 2][ml] = xv.z; xs[k4 + 3][ml] = xv.w;
    ws[k4 + 0][ml] = wv.x; ws[k4 + 1][ml] = wv.y;
    ws[k4 + 2][ml] = wv.z; ws[k4 + 3][ml] = wv.w;
    __syncthreads();
#pragma unroll
    for (int kk = 0; kk < 16; ++kk) {
      float4 a = *(const float4*)&xs[kk][tm << 2];
      float4 bvec = *(const float4*)&ws[kk][tn << 2];
      float av[4] = {a.x, a.y, a.z, a.w};
      float bv[4] = {bvec.x, bvec.y, bvec.z, bvec.w};
#pragma unroll
      for (int mi = 0; mi < 4; ++mi)
#pragma unroll
        for (int ni = 0; ni < 4; ++ni)
          acc[mi][ni] = fmaf(av[mi], bv[ni], acc[mi][ni]);
    }
  }
#pragma unroll
  for (int mi = 0; mi < 4; ++mi) {
    float4 o = {acc[mi][0], acc[mi][1], acc[mi][2], acc[mi][3]};
    *(float4*)(proj + (size_t)(bm0 + (tm << 2) + mi) * 256 + g * 64 + (tn << 2)) = o;
  }
}

// ---------------- Sequential scan ----------------
// One block per batch b. 256 threads: thread (i = tid>>2, jc = tid&3) owns
// S[b][i][jc*16 .. jc*16+15] in registers. Rows are independent; dots over j
// reduce across the 4 jc-lanes via shfl_xor (lanes differ in tid bits 0..1).
__global__ __launch_bounds__(256) void scan_kernel(
    const float* __restrict__ proj, const float* __restrict__ S0,
    const float* __restrict__ d_alpha, const float* __restrict__ b_alpha,
    float* __restrict__ out, float* __restrict__ Sout) {
  const int b = blockIdx.x;
  const int tid = threadIdx.x;
  const int i = tid >> 2;
  const int jc = tid & 3;
  const int j0 = jc << 4;

  __shared__ __align__(16) float buf[2][256];  // per-step [k(64) v(64) q(64) ax(64)]

  float s[16];
#pragma unroll
  for (int r = 0; r < 4; ++r) {
    float4 v = *(const float4*)(S0 + ((size_t)b * NST + i) * NST + j0 + (r << 2));
    s[r * 4 + 0] = v.x; s[r * 4 + 1] = v.y; s[r * 4 + 2] = v.z; s[r * 4 + 3] = v.w;
  }
  const float da = d_alpha[i];
  const float ba = b_alpha[i];

  if (tid < 64) {
    float4 p = *(const float4*)(proj + ((size_t)(0 * BATCH + b) << 8) + (tid << 2));
    *(float4*)&buf[0][tid << 2] = p;
  }
  __syncthreads();

  for (int t = 0; t < T_STEPS; ++t) {
    // issue next step's global load early (latency hiding)
    float4 pre;
    const bool do_stage = (t + 1 < T_STEPS) && (tid < 64);
    if (do_stage)
      pre = *(const float4*)(proj + ((size_t)((t + 1) * BATCH + b) << 8) + (tid << 2));

    const float* P = buf[t & 1];
    float kv[16], qv[16];
#pragma unroll
    for (int r = 0; r < 4; ++r) {
      float4 kk = *(const float4*)&P[j0 + (r << 2)];
      float4 qq = *(const float4*)&P[128 + j0 + (r << 2)];
      kv[r * 4 + 0] = kk.x; kv[r * 4 + 1] = kk.y;
      kv[r * 4 + 2] = kk.z; kv[r * 4 + 3] = kk.w;
      qv[r * 4 + 0] = qq.x; qv[r * 4 + 1] = qq.y;
      qv[r * 4 + 2] = qq.z; qv[r * 4 + 3] = qq.w;
    }
    const float vi = P[64 + i];
    const float axi = P[192 + i];

    // retrieved = S[i,:] . k
    float p0 = 0.f, p1 = 0.f, p2 = 0.f, p3 = 0.f;
#pragma unroll
    for (int r = 0; r < 4; ++r) {
      p0 = fmaf(s[r * 4 + 0], kv[r * 4 + 0], p0);
      p1 = fmaf(s[r * 4 + 1], kv[r * 4 + 1], p1);
      p2 = fmaf(s[r * 4 + 2], kv[r * 4 + 2], p2);
      p3 = fmaf(s[r * 4 + 3], kv[r * 4 + 3], p3);
    }
    float rr = (p0 + p1) + (p2 + p3);
    rr += __shfl_xor(rr, 1);
    rr += __shfl_xor(rr, 2);

    const float alpha = fast_sigmoid(fmaf(da, rr, axi + ba));
    const float c = (1.0f - alpha) * vi;

    // S update + h = S_new[i,:] . q
    float h0 = 0.f, h1 = 0.f, h2 = 0.f, h3 = 0.f;
#pragma unroll
    for (int r = 0; r < 4; ++r) {
      s[r * 4 + 0] = fmaf(alpha, s[r * 4 + 0], c * kv[r * 4 + 0]);
      s[r * 4 + 1] = fmaf(alpha, s[r * 4 + 1], c * kv[r * 4 + 1]);
      s[r * 4 + 2] = fmaf(alpha, s[r * 4 + 2], c * kv[r * 4 + 2]);
      s[r * 4 + 3] = fmaf(alpha, s[r * 4 + 3], c * kv[r * 4 + 3]);
      h0 = fmaf(s[r * 4 + 0], qv[r * 4 + 0], h0);
      h1 = fmaf(s[r * 4 + 1], qv[r * 4 + 1], h1);
      h2 = fmaf(s[r * 4 + 2], qv[r * 4 + 2], h2);
      h3 = fmaf(s[r * 4 + 3], qv[r * 4 + 3], h3);
    }
    float h = (h0 + h1) + (h2 + h3);
    h += __shfl_xor(h, 1);
    h += __shfl_xor(h, 2);

    if (jc == 0) {
      out[((size_t)t * BATCH + b) * NST + i] = h * h * fast_sigmoid(h);
    }

    if (do_stage) *(float4*)&buf[(t + 1) & 1][tid << 2] = pre;
    __syncthreads();
  }

#pragma unroll
  for (int r = 0; r < 4; ++r) {
    float4 o = {s[r * 4 + 0], s[r * 4 + 1], s[r * 4 + 2], s[r * 4 + 3]};
    *(float4*)(Sout + ((size_t)b * NST + i) * NST + j0 + (r << 2)) = o;
  }
}

extern "C" void kernel_launch(void* const* d_in, const int* in_sizes, int n_in,
                              void* d_out, int out_size, void* d_ws, size_t ws_size,
                              hipStream_t stream) {
  const float* x  = (const float*)d_in[0];
  const float* S0 = (const float*)d_in[1];
  const float* Wk = (const float*)d_in[2];
  const float* Wv = (const float*)d_in[3];
  const float* Wq = (const float*)d_in[4];
  const float* Wa = (const float*)d_in[5];
  const float* da = (const float*)d_in[6];
  const float* ba = (const float*)d_in[7];

  float* out  = (float*)d_out;                                  // [T,B,64]
  float* Sout = out + (size_t)T_STEPS * BATCH * NST;            // [B,64,64]
  float* proj = (float*)d_ws;                                   // [16384][256] = 16 MB

  dim3 ggrid(16384 / 64, 4);
  proj_gemm<<<ggrid, 256, 0, stream>>>(x, Wk, Wv, Wq, Wa, proj);
  scan_kernel<<<BATCH, 256, 0, stream>>>(proj, S0, da, ba, out, Sout);
}